// Round 3
// baseline (137.838 us; speedup 1.0000x reference)
//
#include <hip/hip_runtime.h>

// T=6, B=2, Q=50 -> P=100 queries; N=8 targets; 72x72 -> 288x288 bilinear
// (align_corners=False, exact 4x => fixed weights); out C[B,Q,N] = 800 f32.
// R3: 4x4-output tile per thread-iter (one input cell), compile-time weights,
// packed f32x2 math across the query pair, widened sumg.

#define T_      6
#define P_      100
#define N_      8
#define HIN     72
#define HOUT    288
#define S_OUT   (HOUT*HOUT)      // 82944
#define NQUAD   (S_OUT/4)        // 20736 float4 quads per mask
#define NTILE   (HIN*HIN)        // 5184 4x4-output tiles per mask
#define SPLIT   6
#define TPS     (NTILE/SPLIT)    // 864 tiles per block
#define NPAIR   (P_/2)           // 50 query-pairs
#define PART_K  40               // partial floats per (t,pair,split) slot
#define GCHUNK  8
#define SUMG_OFF (T_*NPAIR*SPLIT*PART_K)   // 72000 floats

typedef __attribute__((ext_vector_type(2))) float f32x2;

// packed fma, src1 broadcast LOW half: d = a * (b.x,b.x) + c
__device__ __forceinline__ f32x2 pkfma_bl(f32x2 a, f32x2 b, f32x2 c) {
    f32x2 d;
    asm("v_pk_fma_f32 %0, %1, %2, %3 op_sel:[0,0,0] op_sel_hi:[1,0,1]"
        : "=v"(d) : "v"(a), "v"(b), "v"(c));
    return d;
}
// packed fma, src1 broadcast HIGH half: d = a * (b.y,b.y) + c
__device__ __forceinline__ f32x2 pkfma_bh(f32x2 a, f32x2 b, f32x2 c) {
    f32x2 d;
    asm("v_pk_fma_f32 %0, %1, %2, %3 op_sel:[0,1,0] op_sel_hi:[1,1,1]"
        : "=v"(d) : "v"(a), "v"(b), "v"(c));
    return d;
}

__device__ __forceinline__ f32x2 sigm2(f32x2 u) {
    f32x2 e;
    e.x = __expf(-u.x);                      // v_mul(-log2e) + v_exp
    e.y = __expf(-u.y);
    f32x2 d = e + 1.0f;                      // v_pk_add
    f32x2 r;
    r.x = __builtin_amdgcn_rcpf(d.x);
    r.y = __builtin_amdgcn_rcpf(d.y);
    return r;
}

#define WRED(x) { x += __shfl_down(x,32); x += __shfl_down(x,16); x += __shfl_down(x,8); \
                  x += __shfl_down(x,4);  x += __shfl_down(x,2);  x += __shfl_down(x,1); }
#define WREDP(v) { f32x2 o_; \
    o_.x=__shfl_down(v.x,32); o_.y=__shfl_down(v.y,32); v+=o_; \
    o_.x=__shfl_down(v.x,16); o_.y=__shfl_down(v.y,16); v+=o_; \
    o_.x=__shfl_down(v.x, 8); o_.y=__shfl_down(v.y, 8); v+=o_; \
    o_.x=__shfl_down(v.x, 4); o_.y=__shfl_down(v.y, 4); v+=o_; \
    o_.x=__shfl_down(v.x, 2); o_.y=__shfl_down(v.y, 2); v+=o_; \
    o_.x=__shfl_down(v.x, 1); o_.y=__shfl_down(v.y, 1); v+=o_; }

// ---------------------------------------------------------------------------
// Kernel 1: per (t, query-pair, tile-split) partial sums. 4x4-output tiles.
// ---------------------------------------------------------------------------
__global__ __launch_bounds__(256) void partial_kernel(
    const float* __restrict__ predL, const float* __restrict__ predS,
    const float* __restrict__ tgt, float* __restrict__ ws)
{
    const int blk = blockIdx.x;              // t*(NPAIR*SPLIT) + pr*SPLIT + sp
    const int t   = blk / (NPAIR*SPLIT);
    const int rem = blk % (NPAIR*SPLIT);
    const int pr  = rem / SPLIT;
    const int sp  = rem % SPLIT;

    const float* __restrict__ pL0 = predL + ((size_t)t*P_ + pr*2) * (HIN*HIN);
    const float* __restrict__ pL1 = pL0 + HIN*HIN;
    const float* __restrict__ pS0 = predS + ((size_t)t*P_ + pr*2) * (HIN*HIN);
    const float* __restrict__ pS1 = pS0 + HIN*HIN;
    const float4* __restrict__ g4 = (const float4*)(tgt + (size_t)t*N_*S_OUT);

    f32x2 dL[8], dS[8];
#pragma unroll
    for (int n = 0; n < 8; n++) { dL[n] = (f32x2)(0.f); dS[n] = (f32x2)(0.f); }
    f32x2 sL = (f32x2)(0.f), sS = (f32x2)(0.f), iN = (f32x2)(0.f), iD = (f32x2)(0.f);

    const int tend = (sp+1)*TPS;
    for (int tt = sp*TPS + threadIdx.x; tt < tend; tt += 256) {
        const int j = tt / HIN;
        const int i = tt - j*HIN;
        const int rm = max(j-1,0)*HIN, rc = j*HIN, rp = min(j+1,HIN-1)*HIN;
        const int cm = max(i-1,0),     cp = min(i+1,HIN-1);
        int o[9];
        o[0]=rm+cm; o[1]=rm+i; o[2]=rm+cp;
        o[3]=rc+cm; o[4]=rc+i; o[5]=rc+cp;
        o[6]=rp+cm; o[7]=rp+i; o[8]=rp+cp;

        f32x2 L[9], S[9];
#pragma unroll
        for (int k = 0; k < 9; k++) {
            L[k].x = pL0[o[k]]; L[k].y = pL1[o[k]];
            S[k].x = pS0[o[k]]; S[k].y = pS1[o[k]];
        }

        const float4* __restrict__ gbase = g4 + (size_t)(4*j)*HIN + i;

#pragma unroll
        for (int r = 0; r < 4; r++) {
            const int top = (r < 2) ? 0 : 3;
            const int bot = (r < 2) ? 3 : 6;
            const float wt = (r==0)?0.375f:(r==1)?0.125f:(r==2)?0.875f:0.625f;
            const float wb = 1.0f - wt;

            f32x2 vL[3], vS[3];
#pragma unroll
            for (int c = 0; c < 3; c++) {
                vL[c] = L[top+c]*wt + L[bot+c]*wb;   // pk_mul + pk_fma
                vS[c] = S[top+c]*wt + S[bot+c]*wb;
            }
            f32x2 uL[4], uS[4];
            uL[0] = vL[0]*0.375f + vL[1]*0.625f;
            uL[1] = vL[0]*0.125f + vL[1]*0.875f;
            uL[2] = vL[1]*0.875f + vL[2]*0.125f;
            uL[3] = vL[1]*0.625f + vL[2]*0.375f;
            uS[0] = vS[0]*0.375f + vS[1]*0.625f;
            uS[1] = vS[0]*0.125f + vS[1]*0.875f;
            uS[2] = vS[1]*0.875f + vS[2]*0.125f;
            uS[3] = vS[1]*0.625f + vS[2]*0.375f;

            f32x2 aL[4], aS[4];
#pragma unroll
            for (int k = 0; k < 4; k++) { aL[k] = sigm2(uL[k]); aS[k] = sigm2(uS[k]); }

            // iou + sums
#pragma unroll
            for (int k = 0; k < 4; k++) {
                f32x2 pl, ps;
                pl.x = (uL[k].x > 0.f) ? aL[k].x : 0.f;
                pl.y = (uL[k].y > 0.f) ? aL[k].y : 0.f;
                ps.x = (uS[k].x > 0.f) ? aS[k].x : 0.f;
                ps.y = (uS[k].y > 0.f) ? aS[k].y : 0.f;
                iN = pl*ps + iN;   // pk_fma
                iD = iD + pl;
                sL = sL + aL[k];
                sS = sS + aS[k];
            }

            // dice dot against 8 targets
            const float4* __restrict__ gr = gbase + r*HIN;
#pragma unroll
            for (int n = 0; n < 8; n++) {
                float4 g = gr[n*NQUAD];
                f32x2 gxy; gxy.x = g.x; gxy.y = g.y;
                f32x2 gzw; gzw.x = g.z; gzw.y = g.w;
                dL[n] = pkfma_bl(aL[0], gxy, dL[n]);
                dL[n] = pkfma_bh(aL[1], gxy, dL[n]);
                dL[n] = pkfma_bl(aL[2], gzw, dL[n]);
                dL[n] = pkfma_bh(aL[3], gzw, dL[n]);
                dS[n] = pkfma_bl(aS[0], gxy, dS[n]);
                dS[n] = pkfma_bh(aS[1], gxy, dS[n]);
                dS[n] = pkfma_bl(aS[2], gzw, dS[n]);
                dS[n] = pkfma_bh(aS[3], gzw, dS[n]);
            }
        }
    }

    // packed wave reduction, then cross-wave via LDS
#pragma unroll
    for (int n = 0; n < 8; n++) { WREDP(dL[n]); WREDP(dS[n]); }
    WREDP(sL); WREDP(sS); WREDP(iN); WREDP(iD);

    __shared__ float red[4][PART_K];
    const int lane = threadIdx.x & 63, wv = threadIdx.x >> 6;
    if (lane == 0) {
        float* r = red[wv];
#pragma unroll
        for (int n = 0; n < 8; n++) { r[n]=dL[n].x; r[8+n]=dS[n].x; r[20+n]=dL[n].y; r[28+n]=dS[n].y; }
        r[16]=sL.x; r[17]=sS.x; r[18]=iN.x; r[19]=iD.x;
        r[36]=sL.y; r[37]=sS.y; r[38]=iN.y; r[39]=iD.y;
    }
    __syncthreads();
    if (threadIdx.x < PART_K) {
        float v = red[0][threadIdx.x] + red[1][threadIdx.x]
                + red[2][threadIdx.x] + red[3][threadIdx.x];
        ws[(size_t)blk * PART_K + threadIdx.x] = v;
    }
}

// ---------------------------------------------------------------------------
// Kernel 2: per-(t,n) target mask partial sums, GCHUNK chunks each
// ---------------------------------------------------------------------------
__global__ __launch_bounds__(256) void sumg_kernel(
    const float* __restrict__ tgt, float* __restrict__ ws)
{
    const int blk  = blockIdx.x;             // (t*8+n)*GCHUNK + c
    const int mask = blk / GCHUNK;
    const int c    = blk % GCHUNK;
    const float4* __restrict__ g = (const float4*)(tgt + (size_t)mask*S_OUT);
    const int per = NQUAD / GCHUNK;          // 2592
    float s = 0.f;
    const int end = (c+1)*per;
    for (int idx = c*per + threadIdx.x; idx < end; idx += 256) {
        float4 v = g[idx];
        s += v.x + v.y + v.z + v.w;
    }
    WRED(s);
    __shared__ float r[4];
    if ((threadIdx.x & 63) == 0) r[threadIdx.x >> 6] = s;
    __syncthreads();
    if (threadIdx.x == 0) ws[SUMG_OFF + blk] = r[0]+r[1]+r[2]+r[3];
}

// ---------------------------------------------------------------------------
// Kernel 3: finalize 800 outputs
// ---------------------------------------------------------------------------
__global__ __launch_bounds__(64) void final_kernel(
    const float* __restrict__ pirL, const float* __restrict__ pirS,
    const int* __restrict__ refidx, const float* __restrict__ ws,
    float* __restrict__ out)
{
    const int gid = blockIdx.x*64 + threadIdx.x;
    if (gid >= P_*N_) return;
    const int p = gid >> 3, n = gid & 7;
    const int b = p / 50, q = p % 50;
    const int pr = p >> 1, koff = (p & 1) ? 20 : 0;
    const int rg0 = refidx[0], rg1 = refidx[1] + 4;   // ref_indices[b] + b*(N/B)
    const bool isref = (n == rg0) || (n == rg1);

    float acc = 0.f;
    for (int t = 0; t < T_; t++) {
        const float* base = ws + (size_t)((t*NPAIR + pr)*SPLIT) * PART_K + koff;
        float dL=0.f, dS=0.f, sL=0.f, sS=0.f, iN=0.f, iD=0.f;
#pragma unroll
        for (int sp = 0; sp < SPLIT; sp++) {
            const float* bs = base + sp*PART_K;
            dL += bs[n]; dS += bs[8+n];
            sL += bs[16]; sS += bs[17]; iN += bs[18]; iD += bs[19];
        }
        float gS = 0.f;
#pragma unroll
        for (int c = 0; c < GCHUNK; c++) gS += ws[SUMG_OFF + (t*8+n)*GCHUNK + c];

        const float diceL = (2.f*dL + 1.f) / (sL + gS + 1.f);
        const float diceS = (2.f*dS + 1.f) / (sS + gS + 1.f);
        const float iou   = (iN + 1.f) / (iD + 1.f);
        const int ib = ((t*2 + b)*50 + q)*2;
        const float l0 = pirL[ib], l1 = pirL[ib+1];
        const float m0 = pirS[ib], m1 = pirS[ib+1];
        const float pl = isref ? 1.f/(1.f + __expf(l1 - l0)) : 1.f/(1.f + __expf(l0 - l1));
        const float ps = isref ? 1.f/(1.f + __expf(m1 - m0)) : 1.f/(1.f + __expf(m0 - m1));
        acc += diceL + diceS + iou + pl + ps;
    }
    out[gid] = -acc * (1.0f / (float)T_);
}

extern "C" void kernel_launch(void* const* d_in, const int* in_sizes, int n_in,
                              void* d_out, int out_size, void* d_ws, size_t ws_size,
                              hipStream_t stream) {
    const float* predL = (const float*)d_in[0];   // [6,2,50,72,72]
    const float* predS = (const float*)d_in[1];   // [6,2,50,72,72]
    const float* pirL  = (const float*)d_in[2];   // [6,2,50,2]
    const float* pirS  = (const float*)d_in[3];   // [6,2,50,2]
    const float* tgt   = (const float*)d_in[4];   // [6,8,288,288]
    const int*   refix = (const int*)d_in[5];     // [2]
    float* ws  = (float*)d_ws;                    // 72384 floats (~290 KiB)
    float* out = (float*)d_out;                   // 800 floats

    sumg_kernel<<<T_*N_*GCHUNK, 256, 0, stream>>>(tgt, ws);
    partial_kernel<<<T_*NPAIR*SPLIT, 256, 0, stream>>>(predL, predS, tgt, ws);
    final_kernel<<<(P_*N_ + 63)/64, 64, 0, stream>>>(pirL, pirS, refix, ws, out);
}